// Round 13
// baseline (66.575 us; speedup 1.0000x reference)
//
#include <hip/hip_runtime.h>
#include <math.h>

#define NSAMP   32768
#define NFRAMES 128
#define NHARM   16
#define BATCH   64
#define MFFT    16384          // complex FFT size (even/odd real pack), = 128*128
#define ZROW    137            // LDS row stride (float2) per 128-entry FFT row

static __device__ __forceinline__ float clampf(float x, float lo, float hi) {
  return fminf(fmaxf(x, lo), hi);
}
static __device__ __forceinline__ int zp(int fft, int p) {        // LDS swizzle
  return fft * ZROW + p + (p >> 4);
}
static __device__ __forceinline__ int brev7(int n) {
  return (int)(__brev((unsigned)n) >> 25);
}
static __device__ __forceinline__ float2 cmulf(float c, float s, float2 v) {
  return make_float2(c * v.x - s * v.y, c * v.y + s * v.x);
}
static __device__ __forceinline__ float2 f2add(float2 a, float2 b) {
  return make_float2(a.x + b.x, a.y + b.y);
}
static __device__ __forceinline__ float2 f2sub(float2 a, float2 b) {
  return make_float2(a.x - b.x, a.y - b.y);
}

static __device__ __forceinline__ void tw_init(float2* tws, int tid) {
  if (tid < 64) {
    float s, c;
    __sincosf(-(float)M_PI * (float)tid * (1.0f / 64.0f), &s, &c);
    tws[tid] = make_float2(c, s);
  }
}

// ---------------------------------------------------------------------------
// 4 FFTs of length 128 in LDS, 128 threads, radix-4 fused stage-pairs
// (3 radix-4 + 1 radix-2). DIT: bit-reversed input -> natural output.
// tws[j] = e^{-i pi j/64}; INV conjugates; w2b = (fwd) -i*w2a / (inv) +i*w2a.
// ---------------------------------------------------------------------------
template <bool INV>
static __device__ __forceinline__ void fft128_r4(float2* zs, const float2* tws, int tid) {
  int fft = tid >> 5, i = tid & 31;
  #pragma unroll
  for (int s = 0; s < 6; s += 2) {
    int half = 1 << s;
    int kk1 = i & (half - 1);
    int base = ((i & ~(half - 1)) << 2) | kk1;
    int p0 = zp(fft, base),            p1 = zp(fft, base + half);
    int p2 = zp(fft, base + 2 * half), p3 = zp(fft, base + 3 * half);
    float2 q0 = zs[p0], q1 = zs[p1], q2 = zs[p2], q3 = zs[p3];
    float2 t1 = tws[kk1 << (6 - s)], t2 = tws[kk1 << (5 - s)];
    float c1 = t1.x, s1 = INV ? -t1.y : t1.y;
    float c2 = t2.x, s2 = INV ? -t2.y : t2.y;
    float c2b = INV ? -s2 : s2, s2b = INV ? c2 : -c2;
    float2 t;
    t = cmulf(c1, s1, q1);   float2 A0 = f2add(q0, t), A1 = f2sub(q0, t);
    t = cmulf(c1, s1, q3);   float2 A2 = f2add(q2, t), A3 = f2sub(q2, t);
    t = cmulf(c2, s2, A2);   zs[p0] = f2add(A0, t); zs[p2] = f2sub(A0, t);
    t = cmulf(c2b, s2b, A3); zs[p1] = f2add(A1, t); zs[p3] = f2sub(A1, t);
    __syncthreads();
  }
  #pragma unroll
  for (int j = tid; j < 256; j += 128) {           // stage 6, radix-2
    int f = j >> 6, kk = j & 63;
    float2 w = tws[kk];
    float cc = w.x, ss = INV ? -w.y : w.y;
    int a0 = zp(f, kk), a1 = zp(f, kk + 64);
    float2 a = zs[a0], bv = zs[a1];
    float2 t = cmulf(cc, ss, bv);
    zs[a0] = f2add(a, t); zs[a1] = f2sub(a, t);
  }
  __syncthreads();
}

// Inverse as DIF: natural input -> bit-reversed output. Stage 6 first, then
// fused pairs (5,4),(3,2),(1,0). Twiddles conjugated; w2b = +i*w2a.
static __device__ __forceinline__ void fft128_r4_dif_inv(float2* zs, const float2* tws, int tid) {
  #pragma unroll
  for (int j = tid; j < 256; j += 128) {           // stage 6, radix-2 DIF
    int f = j >> 6, kk = j & 63;
    float2 w = tws[kk];
    float cc = w.x, ss = -w.y;
    int a0 = zp(f, kk), a1 = zp(f, kk + 64);
    float2 u = zs[a0], v = zs[a1];
    zs[a0] = f2add(u, v);
    zs[a1] = cmulf(cc, ss, f2sub(u, v));
  }
  __syncthreads();
  int fft = tid >> 5, i = tid & 31;
  #pragma unroll
  for (int s = 4; s >= 0; s -= 2) {
    int half = 1 << s;
    int kk1 = i & (half - 1);
    int base = ((i & ~(half - 1)) << 2) | kk1;
    int p0 = zp(fft, base),            p1 = zp(fft, base + half);
    int p2 = zp(fft, base + 2 * half), p3 = zp(fft, base + 3 * half);
    float2 q0 = zs[p0], q1 = zs[p1], q2 = zs[p2], q3 = zs[p3];
    float2 t1 = tws[kk1 << (6 - s)], t2 = tws[kk1 << (5 - s)];
    float c1 = t1.x, s1 = -t1.y;
    float c2 = t2.x, s2 = -t2.y;
    float c2b = -s2, s2b = c2;                  // +i * (c2, s2)
    float2 B0 = f2add(q0, q2);
    float2 B2 = cmulf(c2, s2, f2sub(q0, q2));
    float2 B1 = f2add(q1, q3);
    float2 B3 = cmulf(c2b, s2b, f2sub(q1, q3));
    zs[p0] = f2add(B0, B1);
    zs[p1] = cmulf(c1, s1, f2sub(B0, B1));
    zs[p2] = f2add(B2, B3);
    zs[p3] = cmulf(c1, s1, f2sub(B2, B3));
    __syncthreads();
  }
}

static __device__ __forceinline__ float h_filter(int f, const float* nf_s) {
  float coords = ((float)f + 0.5f) * (1.0f / 256.0f) - 0.5f;
  coords = clampf(coords, 0.0f, 63.0f);
  int i0 = (int)coords;
  int i1 = (i0 < 63) ? (i0 + 1) : 63;
  float w = coords - (float)i0;
  return nf_s[i0] * (1.0f - w) + nf_s[i1] * w;
}

static __device__ __forceinline__ float amp_lerp(int s, const float* amp_s) {
  float coords = ((float)s + 0.5f) * (1.0f / 256.0f) - 0.5f;
  coords = clampf(coords, 0.0f, 127.0f);
  int i0 = (int)coords;
  int i1 = (i0 < 127) ? (i0 + 1) : 127;
  float w = coords - (float)i0;
  float v = amp_s[i0] * (1.0f - w) + amp_s[i1] * w;
  return clampf(v, 0.0f, 1.0f);
}

// ---------------------------------------------------------------------------
// k1 body (kf1's blockIdx.y==0 slice): gumbel argmax -> f0 -> radians (f64);
// 128-frame env scan. env layout: env_ws[frame*1024 + channel]
// ---------------------------------------------------------------------------
static __device__ void k1_body(
    const float* __restrict__ packed, const float* __restrict__ gumbel,
    double* __restrict__ r64_ws, float* __restrict__ env_ws, int b, int tid) {
  __shared__ double zv[128];
  __shared__ int    zi[128];
  __shared__ double f0_sh;
  const float* pk = packed + b * 480;

  double u = (double)gumbel[b * 128 + tid];
  double t = -log(u + 1e-10);
  double g = -log(t + 1e-10);
  zv[tid] = (double)pk[tid] + g;
  zi[tid] = tid;
  __syncthreads();
  for (int s = 64; s > 0; s >>= 1) {
    if (tid < s) {
      double a = zv[tid], c = zv[tid + s];
      int ia = zi[tid], ic = zi[tid + s];
      if (c > a || (c == a && ic < ia)) { zv[tid] = c; zi[tid] = ic; }
    }
    __syncthreads();
  }
  if (tid == 0) {
    int note = zi[0];
    double Fd  = 440.0 * exp2(((double)(note - 69)) / 12.0) / 11025.0;
    float  F32 = (float)Fd;                     // FREQS is f32 in the reference
    double f0  = (double)F32 * 11025.0;
    f0 = (40.0 / 11025.0) + f0 * (3000.0 / 11025.0 - 40.0 / 11025.0);
    f0_sh = f0;
  }
  __syncthreads();
  if (tid < NHARM) {
    int h = tid;
    int c = b * NHARM + h;
    const float PIF = 3.14159265358979323846f;  // float32(np.pi)
    double osc = f0_sh * (double)(h + 1);
    r64_ws[c] = (osc / 11025.0) * (double)PIF;
    float ha = pk[384 + h];
    float hd = 0.1f + pk[400 + h] * 0.9f;
    float cur = 0.0f;
    for (int tt = 0; tt < NFRAMES; ++tt) {
      float a = pk[256 + tt] * 2.0f - 1.0f;
      cur = clampf(cur + a * ha, 0.0f, 1.0f);
      env_ws[tt * 1024 + c] = cur;
      cur = cur * hd;
    }
  }
}

// ---------------------------------------------------------------------------
// kernel 1 -- kf1: column FFTs (length 128 over n1) + W_M^{n2 k1} twiddle;
// blockIdx.y==0 runs k1. grid (BATCH, 33) x 128; 4 columns per FFT WG.
// ---------------------------------------------------------------------------
__global__ __launch_bounds__(128, 4) void kf1(
    const float* __restrict__ noise_u, float2* __restrict__ A,
    const float* __restrict__ packed, const float* __restrict__ gumbel,
    double* __restrict__ r64_ws, float* __restrict__ env_ws) {
  int b = blockIdx.x, tid = threadIdx.x;
  if (blockIdx.y == 0) { k1_body(packed, gumbel, r64_ws, env_ws, b, tid); return; }
  int tile = blockIdx.y - 1;
  __shared__ float2 zs[4 * ZROW];
  __shared__ float2 tws[64];
  tw_init(tws, tid);
  const float2* nu2 = (const float2*)(noise_u + (size_t)b * NSAMP);
  #pragma unroll
  for (int it = 0; it < 4; ++it) {
    int e = it * 128 + tid;
    int n1 = e >> 2, n2l = e & 3;
    float2 xv = nu2[n1 * 128 + tile * 4 + n2l];
    zs[zp(n2l, brev7(n1))] = make_float2(xv.x * 2.0f - 1.0f, xv.y * 2.0f - 1.0f);
  }
  __syncthreads();
  fft128_r4<false>(zs, tws, tid);
  float2* Ab = A + (size_t)b * MFFT;
  #pragma unroll
  for (int it = 0; it < 4; ++it) {
    int e = it * 128 + tid;
    int k1 = e >> 2, n2l = e & 3;
    int n2 = tile * 4 + n2l;
    float2 v = zs[zp(n2l, k1)];
    float ang = -(2.0f * (float)M_PI / 16384.0f) * (float)(k1 * n2);
    float ss, cc; __sincosf(ang, &ss, &cc);
    Ab[k1 * 128 + n2] = make_float2(cc * v.x - ss * v.y, cc * v.y + ss * v.x);
  }
}

// ---------------------------------------------------------------------------
// kernel 2 -- kmid: fused row-FFT (fwd) -> Hermitian filter (LDS) ->
// row-IFFT (DIF) -> conj twiddle. 4 rows = 2 pair-groups per WG.
// PLUS: each WG computes one independent 16-sample oscillator-bank slice
// (Chebyshev harmonic recurrence; r64/env from kernel 1) and plain-stores
// osc/1024 to out -- covers out exactly once and un-poisons it.
// grid (BATCH, 32) x 128
// ---------------------------------------------------------------------------
__global__ __launch_bounds__(128, 4) void kmid(
    const float* __restrict__ packed, float2* __restrict__ A,
    const double* __restrict__ r64_ws, const float* __restrict__ env_ws,
    float* __restrict__ out) {
  __shared__ float2 zs[4 * ZROW];
  __shared__ float2 tws[64];
  __shared__ float  nf_s[64];
  __shared__ int    rowk1[4];
  int b = blockIdx.x, t = blockIdx.y, tid = threadIdx.x;
  tw_init(tws, tid);
  if (tid >= 64 && tid < 128) nf_s[tid - 64] = packed[b * 480 + 416 + (tid - 64)];
  if (tid < 4) {
    int s = tid & 1;
    int m = t * 2 + s;
    rowk1[tid] = (tid < 2) ? m : ((m == 0) ? 64 : 128 - m);
  }
  __syncthreads();
  float2* Ab = A + (size_t)b * MFFT;

  #pragma unroll
  for (int it = 0; it < 4; ++it) {
    int e = it * 128 + tid;
    int r = e >> 7, n2 = e & 127;
    zs[zp(r, brev7(n2))] = Ab[rowk1[r] * 128 + n2];
  }
  __syncthreads();
  fft128_r4<false>(zs, tws, tid);   // zs[zp(r,k2)] = Z[rowk1[r] + 128*k2]

  const float hsc = 1.0f / 16384.0f;
  #pragma unroll
  for (int it = 0; it < 2; ++it) {
    int task = it * 128 + tid;      // 256 tasks: (local row r, k2 in 0..63)
    int r  = task >> 6;
    int k2 = task & 63;
    int k1 = rowk1[r];
    int f = k1 + (k2 << 7);
    if (f == 0) {                   // DC and f=8192 specials (WG t=0 only)
      float2 Z0 = zs[zp(0, 0)];
      float X0 = Z0.x + Z0.y;
      float Y0 = X0 * (h_filter(0, nf_s) * hsc);
      zs[zp(0, 0)] = make_float2(0.5f * Y0, 0.5f * Y0);   // H[M]=0 -> YM=0
      float Hm = h_filter(8192, nf_s) * hsc;
      float2 Zm = zs[zp(0, 64)];
      zs[zp(0, 64)] = make_float2(Zm.x * Hm, Zm.y * Hm);
    } else {
      int g = 16384 - f;
      int k1g = g & 127;
      int pr = (k1g == k1) ? r : ((r < 2) ? r + 2 : r - 2);
      int k2p = g >> 7;
      float2 Zf = zs[zp(r, k2)], Zg = zs[zp(pr, k2p)];
      float Ax = 0.5f * (Zf.x + Zg.x), Ay = 0.5f * (Zf.y - Zg.y);
      float Bx = 0.5f * (Zf.x - Zg.x), By = 0.5f * (Zf.y + Zg.y);
      float ang = (-(float)M_PI / (float)MFFT) * (float)f;
      float ss, cc; __sincosf(ang, &ss, &cc);
      float WBx = cc * Bx - ss * By, WBy = cc * By + ss * Bx;
      float Hf = h_filter(f, nf_s) * hsc;
      float Hg = h_filter(g, nf_s) * hsc;
      float Yfx = (Ax + WBy) * Hf, Yfy = (Ay - WBx) * Hf;
      float Ygx = (Ax - WBy) * Hg, Ygy = (-Ay - WBx) * Hg;
      float A2x = 0.5f * (Yfx + Ygx), A2y = 0.5f * (Yfy - Ygy);
      float B2x = 0.5f * (Yfx - Ygx), B2y = 0.5f * (Yfy + Ygy);
      float CBx = cc * B2x + ss * B2y;
      float CBy = cc * B2y - ss * B2x;
      zs[zp(r, k2)]   = make_float2(A2x - CBy, A2y + CBx);
      float DBx = cc * B2x + ss * B2y;
      float DBy = ss * B2x - cc * B2y;
      zs[zp(pr, k2p)] = make_float2(A2x - DBy, -A2y + DBx);
    }
  }
  __syncthreads();

  fft128_r4_dif_inv(zs, tws, tid);  // natural -> bitrev

  #pragma unroll
  for (int it = 0; it < 4; ++it) {
    int e = it * 128 + tid;
    int r = e >> 7, n2 = e & 127;
    int k1 = rowk1[r];
    float2 v = zs[zp(r, brev7(n2))];
    float ang = (2.0f * (float)M_PI / 16384.0f) * (float)(k1 * n2);
    float ss, cc; __sincosf(ang, &ss, &cc);
    Ab[k1 * 128 + n2] = make_float2(cc * v.x - ss * v.y, cc * v.y + ss * v.x);
  }

  // ---- independent oscillator-bank slice (16 samples per WG) ----
  {
    __shared__ float oscs[16];
    const double TWO_PI     = 6.283185307179586476925286766559;
    const double INV_TWO_PI = 0.15915494309189533576888376337251;
    int gid = b * 32 + t;              // 0..2047
    int lane = tid & 63;               // channel-batch
    int w = tid >> 6;                  // wave: 8 samples each
    int chunk = gid >> 3, sub = gid & 7;
    int s0 = chunk * 128 + sub * 16;
    int K = chunk >> 1, half = chunk & 1;

    double r0 = r64_ws[lane * 16];     // fundamental step angle (f64)
    double rr = r0 - rint(r0 * INV_TWO_PI) * TWO_PI;
    double x0 = (double)(s0 + w * 8 + 1) * r0;
    double ph = x0 - rint(x0 * INV_TWO_PI) * TWO_PI;
    float s1, c1, srot, crot;
    __sincosf((float)ph, &s1, &c1);
    __sincosf((float)rr, &srot, &crot);

    int km1 = (K > 0) ? (K - 1) : 0;
    int kp1 = (K < 127) ? (K + 1) : 127;
    int fA = half ? K : km1;
    int fB = half ? kp1 : K;
    const float4* eA = (const float4*)(env_ws + fA * 1024 + lane * 16);
    const float4* eB = (const float4*)(env_ws + fB * 1024 + lane * 16);
    float ev[16], sl[16];
    float basew = (half ? 0.5f : 128.5f) + (float)(sub * 16 + w * 8);
    #pragma unroll
    for (int q = 0; q < 4; ++q) {
      float4 a = eA[q], bb = eB[q];
      float d;
      d = (bb.x - a.x) * (1.0f / 256.0f); sl[q*4+0] = d; ev[q*4+0] = a.x + d * basew;
      d = (bb.y - a.y) * (1.0f / 256.0f); sl[q*4+1] = d; ev[q*4+1] = a.y + d * basew;
      d = (bb.z - a.z) * (1.0f / 256.0f); sl[q*4+2] = d; ev[q*4+2] = a.z + d * basew;
      d = (bb.w - a.w) * (1.0f / 256.0f); sl[q*4+3] = d; ev[q*4+3] = a.w + d * basew;
    }

    #pragma unroll
    for (int j = 0; j < 8; ++j) {
      float twoC = c1 + c1;
      float sm1 = 0.0f, sc = s1;
      float acc = ev[0] * sc; ev[0] += sl[0];
      #pragma unroll
      for (int i = 1; i < 16; ++i) {
        float sn = fmaf(twoC, sc, -sm1);
        sm1 = sc; sc = sn;
        acc = fmaf(ev[i], sn, acc);
        ev[i] += sl[i];
      }
      acc += __shfl_xor(acc, 32);
      acc += __shfl_xor(acc, 16);
      acc += __shfl_xor(acc, 8);
      acc += __shfl_xor(acc, 4);
      acc += __shfl_xor(acc, 2);
      acc += __shfl_xor(acc, 1);
      if (lane == 0) oscs[w * 8 + j] = acc;
      float tn = fmaf(s1, crot, c1 * srot);      // uses old s1,c1
      c1 = fmaf(c1, crot, -(s1 * srot));
      s1 = tn;
    }
    __syncthreads();
    if (tid < 16) out[s0 + tid] = oscs[tid] * (1.0f / 1024.0f);
  }
}

// ---------------------------------------------------------------------------
// kernel 3 -- ki2: column inverse FFTs (over k1) + amp*clip, then
// atomicAdd(v/64) straight into out (batch-mean by linearity; out already
// holds the osc part from kernel 2). grid (BATCH, 32) x 128.
// ---------------------------------------------------------------------------
__global__ __launch_bounds__(128, 4) void ki2(
    const float* __restrict__ packed, const float2* __restrict__ A,
    float* __restrict__ out) {
  __shared__ float2 zs[4 * ZROW];
  __shared__ float2 tws[64];
  __shared__ float amp_s[128];
  int b = blockIdx.x, tile = blockIdx.y, tid = threadIdx.x;
  tw_init(tws, tid);
  amp_s[tid] = packed[b * 480 + 256 + tid] * 2.0f - 1.0f;
  const float2* Ab = A + (size_t)b * MFFT;
  #pragma unroll
  for (int it = 0; it < 4; ++it) {
    int e = it * 128 + tid;
    int k1 = e >> 2, n2l = e & 3;
    zs[zp(n2l, brev7(k1))] = Ab[k1 * 128 + tile * 4 + n2l];
  }
  __syncthreads();
  fft128_r4<true>(zs, tws, tid);
  #pragma unroll
  for (int it = 0; it < 4; ++it) {
    int e = it * 128 + tid;
    int n1 = e >> 2, n2l = e & 3;
    int n2 = tile * 4 + n2l;
    int n = n1 * 128 + n2;
    float2 v = zs[zp(n2l, n1)];
    atomicAdd(&out[2 * n],     v.x * amp_lerp(2 * n,     amp_s) * (1.0f / 64.0f));
    atomicAdd(&out[2 * n + 1], v.y * amp_lerp(2 * n + 1, amp_s) * (1.0f / 64.0f));
  }
}

// ---------------------------------------------------------------------------
extern "C" void kernel_launch(void* const* d_in, const int* in_sizes, int n_in,
                              void* d_out, int out_size, void* d_ws, size_t ws_size,
                              hipStream_t stream) {
  const float* packed  = (const float*)d_in[0];
  const float* gumbel  = (const float*)d_in[1];
  const float* noise_u = (const float*)d_in[2];
  float* out = (float*)d_out;

  // ws layout: [r64 8KB][env 512KB][A 8MB]
  char* wsc = (char*)d_ws;
  double* r64_ws = (double*)wsc;
  float*  env_ws = (float*)(wsc + 8192);
  float2* A      = (float2*)(wsc + 8192 + 524288);

  kf1 <<<dim3(BATCH, 33), 128, 0, stream>>>(noise_u, A, packed, gumbel, r64_ws, env_ws);
  kmid<<<dim3(BATCH, 32), 128, 0, stream>>>(packed, A, r64_ws, env_ws, out);
  ki2 <<<dim3(BATCH, 32), 128, 0, stream>>>(packed, A, out);
}

// Round 14
// 53.283 us; speedup vs baseline: 1.2494x; 1.2494x over previous
//
#include <hip/hip_runtime.h>
#include <math.h>

#define NSAMP   32768
#define NFRAMES 128
#define NHARM   16
#define BATCH   64
#define MFFT    16384          // complex FFT size (even/odd real pack), = 128*128
#define ZROW    137            // LDS row stride (float2) per 128-entry FFT row

static __device__ __forceinline__ float clampf(float x, float lo, float hi) {
  return fminf(fmaxf(x, lo), hi);
}
static __device__ __forceinline__ int zp(int fft, int p) {        // LDS swizzle
  return fft * ZROW + p + (p >> 4);
}
static __device__ __forceinline__ int brev7(int n) {
  return (int)(__brev((unsigned)n) >> 25);
}
static __device__ __forceinline__ float2 cmulf(float c, float s, float2 v) {
  return make_float2(c * v.x - s * v.y, c * v.y + s * v.x);
}
static __device__ __forceinline__ float2 f2add(float2 a, float2 b) {
  return make_float2(a.x + b.x, a.y + b.y);
}
static __device__ __forceinline__ float2 f2sub(float2 a, float2 b) {
  return make_float2(a.x - b.x, a.y - b.y);
}

static __device__ __forceinline__ void tw_init(float2* tws, int tid) {
  if (tid < 64) {
    float s, c;
    __sincosf(-(float)M_PI * (float)tid * (1.0f / 64.0f), &s, &c);
    tws[tid] = make_float2(c, s);
  }
}

// ---------------------------------------------------------------------------
// 4 FFTs of length 128 in LDS, 128 threads, radix-4 fused stage-pairs
// (3 radix-4 + 1 radix-2). DIT: bit-reversed input -> natural output.
// tws[j] = e^{-i pi j/64}; INV conjugates; w2b = (fwd) -i*w2a / (inv) +i*w2a.
// ---------------------------------------------------------------------------
template <bool INV>
static __device__ __forceinline__ void fft128_r4(float2* zs, const float2* tws, int tid) {
  int fft = tid >> 5, i = tid & 31;
  #pragma unroll
  for (int s = 0; s < 6; s += 2) {
    int half = 1 << s;
    int kk1 = i & (half - 1);
    int base = ((i & ~(half - 1)) << 2) | kk1;
    int p0 = zp(fft, base),            p1 = zp(fft, base + half);
    int p2 = zp(fft, base + 2 * half), p3 = zp(fft, base + 3 * half);
    float2 q0 = zs[p0], q1 = zs[p1], q2 = zs[p2], q3 = zs[p3];
    float2 t1 = tws[kk1 << (6 - s)], t2 = tws[kk1 << (5 - s)];
    float c1 = t1.x, s1 = INV ? -t1.y : t1.y;
    float c2 = t2.x, s2 = INV ? -t2.y : t2.y;
    float c2b = INV ? -s2 : s2, s2b = INV ? c2 : -c2;
    float2 t;
    t = cmulf(c1, s1, q1);   float2 A0 = f2add(q0, t), A1 = f2sub(q0, t);
    t = cmulf(c1, s1, q3);   float2 A2 = f2add(q2, t), A3 = f2sub(q2, t);
    t = cmulf(c2, s2, A2);   zs[p0] = f2add(A0, t); zs[p2] = f2sub(A0, t);
    t = cmulf(c2b, s2b, A3); zs[p1] = f2add(A1, t); zs[p3] = f2sub(A1, t);
    __syncthreads();
  }
  #pragma unroll
  for (int j = tid; j < 256; j += 128) {           // stage 6, radix-2
    int f = j >> 6, kk = j & 63;
    float2 w = tws[kk];
    float cc = w.x, ss = INV ? -w.y : w.y;
    int a0 = zp(f, kk), a1 = zp(f, kk + 64);
    float2 a = zs[a0], bv = zs[a1];
    float2 t = cmulf(cc, ss, bv);
    zs[a0] = f2add(a, t); zs[a1] = f2sub(a, t);
  }
  __syncthreads();
}

// Inverse as DIF: natural input -> bit-reversed output. Stage 6 first, then
// fused pairs (5,4),(3,2),(1,0). Twiddles conjugated; w2b = +i*w2a.
static __device__ __forceinline__ void fft128_r4_dif_inv(float2* zs, const float2* tws, int tid) {
  #pragma unroll
  for (int j = tid; j < 256; j += 128) {           // stage 6, radix-2 DIF
    int f = j >> 6, kk = j & 63;
    float2 w = tws[kk];
    float cc = w.x, ss = -w.y;
    int a0 = zp(f, kk), a1 = zp(f, kk + 64);
    float2 u = zs[a0], v = zs[a1];
    zs[a0] = f2add(u, v);
    zs[a1] = cmulf(cc, ss, f2sub(u, v));
  }
  __syncthreads();
  int fft = tid >> 5, i = tid & 31;
  #pragma unroll
  for (int s = 4; s >= 0; s -= 2) {
    int half = 1 << s;
    int kk1 = i & (half - 1);
    int base = ((i & ~(half - 1)) << 2) | kk1;
    int p0 = zp(fft, base),            p1 = zp(fft, base + half);
    int p2 = zp(fft, base + 2 * half), p3 = zp(fft, base + 3 * half);
    float2 q0 = zs[p0], q1 = zs[p1], q2 = zs[p2], q3 = zs[p3];
    float2 t1 = tws[kk1 << (6 - s)], t2 = tws[kk1 << (5 - s)];
    float c1 = t1.x, s1 = -t1.y;
    float c2 = t2.x, s2 = -t2.y;
    float c2b = -s2, s2b = c2;                  // +i * (c2, s2)
    float2 B0 = f2add(q0, q2);
    float2 B2 = cmulf(c2, s2, f2sub(q0, q2));
    float2 B1 = f2add(q1, q3);
    float2 B3 = cmulf(c2b, s2b, f2sub(q1, q3));
    zs[p0] = f2add(B0, B1);
    zs[p1] = cmulf(c1, s1, f2sub(B0, B1));
    zs[p2] = f2add(B2, B3);
    zs[p3] = cmulf(c1, s1, f2sub(B2, B3));
    __syncthreads();
  }
}

static __device__ __forceinline__ float h_filter(int f, const float* nf_s) {
  float coords = ((float)f + 0.5f) * (1.0f / 256.0f) - 0.5f;
  coords = clampf(coords, 0.0f, 63.0f);
  int i0 = (int)coords;
  int i1 = (i0 < 63) ? (i0 + 1) : 63;
  float w = coords - (float)i0;
  return nf_s[i0] * (1.0f - w) + nf_s[i1] * w;
}

static __device__ __forceinline__ float amp_lerp(int s, const float* amp_s) {
  float coords = ((float)s + 0.5f) * (1.0f / 256.0f) - 0.5f;
  coords = clampf(coords, 0.0f, 127.0f);
  int i0 = (int)coords;
  int i1 = (i0 < 127) ? (i0 + 1) : 127;
  float w = coords - (float)i0;
  float v = amp_s[i0] * (1.0f - w) + amp_s[i1] * w;
  return clampf(v, 0.0f, 1.0f);
}

// ---------------------------------------------------------------------------
// k1 body (kf1's blockIdx.y==0 slice): gumbel argmax -> f0 -> radians (f64);
// 128-frame env scan. env layout: env_ws[frame*1024 + channel]
// ---------------------------------------------------------------------------
static __device__ void k1_body(
    const float* __restrict__ packed, const float* __restrict__ gumbel,
    double* __restrict__ r64_ws, float* __restrict__ env_ws, int b, int tid) {
  __shared__ double zv[128];
  __shared__ int    zi[128];
  __shared__ double f0_sh;
  const float* pk = packed + b * 480;

  double u = (double)gumbel[b * 128 + tid];
  double t = -log(u + 1e-10);
  double g = -log(t + 1e-10);
  zv[tid] = (double)pk[tid] + g;
  zi[tid] = tid;
  __syncthreads();
  for (int s = 64; s > 0; s >>= 1) {
    if (tid < s) {
      double a = zv[tid], c = zv[tid + s];
      int ia = zi[tid], ic = zi[tid + s];
      if (c > a || (c == a && ic < ia)) { zv[tid] = c; zi[tid] = ic; }
    }
    __syncthreads();
  }
  if (tid == 0) {
    int note = zi[0];
    double Fd  = 440.0 * exp2(((double)(note - 69)) / 12.0) / 11025.0;
    float  F32 = (float)Fd;                     // FREQS is f32 in the reference
    double f0  = (double)F32 * 11025.0;
    f0 = (40.0 / 11025.0) + f0 * (3000.0 / 11025.0 - 40.0 / 11025.0);
    f0_sh = f0;
  }
  __syncthreads();
  if (tid < NHARM) {
    int h = tid;
    int c = b * NHARM + h;
    const float PIF = 3.14159265358979323846f;  // float32(np.pi)
    double osc = f0_sh * (double)(h + 1);
    r64_ws[c] = (osc / 11025.0) * (double)PIF;
    float ha = pk[384 + h];
    float hd = 0.1f + pk[400 + h] * 0.9f;
    float cur = 0.0f;
    for (int tt = 0; tt < NFRAMES; ++tt) {
      float a = pk[256 + tt] * 2.0f - 1.0f;
      cur = clampf(cur + a * ha, 0.0f, 1.0f);
      env_ws[tt * 1024 + c] = cur;
      cur = cur * hd;
    }
  }
}

// ---------------------------------------------------------------------------
// kernel 1 -- kf1: column FFTs (length 128 over n1) + W_M^{n2 k1} twiddle;
// blockIdx.y==0 runs k1. grid (BATCH, 33) x 128; 4 columns per FFT WG.
// ---------------------------------------------------------------------------
__global__ __launch_bounds__(128, 4) void kf1(
    const float* __restrict__ noise_u, float2* __restrict__ A,
    const float* __restrict__ packed, const float* __restrict__ gumbel,
    double* __restrict__ r64_ws, float* __restrict__ env_ws) {
  int b = blockIdx.x, tid = threadIdx.x;
  if (blockIdx.y == 0) { k1_body(packed, gumbel, r64_ws, env_ws, b, tid); return; }
  int tile = blockIdx.y - 1;
  __shared__ float2 zs[4 * ZROW];
  __shared__ float2 tws[64];
  tw_init(tws, tid);
  const float2* nu2 = (const float2*)(noise_u + (size_t)b * NSAMP);
  #pragma unroll
  for (int it = 0; it < 4; ++it) {
    int e = it * 128 + tid;
    int n1 = e >> 2, n2l = e & 3;
    float2 xv = nu2[n1 * 128 + tile * 4 + n2l];
    zs[zp(n2l, brev7(n1))] = make_float2(xv.x * 2.0f - 1.0f, xv.y * 2.0f - 1.0f);
  }
  __syncthreads();
  fft128_r4<false>(zs, tws, tid);
  float2* Ab = A + (size_t)b * MFFT;
  #pragma unroll
  for (int it = 0; it < 4; ++it) {
    int e = it * 128 + tid;
    int k1 = e >> 2, n2l = e & 3;
    int n2 = tile * 4 + n2l;
    float2 v = zs[zp(n2l, k1)];
    float ang = -(2.0f * (float)M_PI / 16384.0f) * (float)(k1 * n2);
    float ss, cc; __sincosf(ang, &ss, &cc);
    Ab[k1 * 128 + n2] = make_float2(cc * v.x - ss * v.y, cc * v.y + ss * v.x);
  }
}

// ---------------------------------------------------------------------------
// kernel 2 -- kmid: fused row-FFT (fwd) -> Hermitian filter (LDS) ->
// row-IFFT (DIF) -> conj twiddle. 4 rows = 2 pair-groups per WG.
// PLUS: each WG computes one independent 16-sample oscillator-bank slice
// (Chebyshev harmonic recurrence) and plain-stores osc/1024 to out --
// covers out exactly once and un-poisons it. grid (BATCH, 32) x 128
// ---------------------------------------------------------------------------
__global__ __launch_bounds__(128, 4) void kmid(
    const float* __restrict__ packed, float2* __restrict__ A,
    const double* __restrict__ r64_ws, const float* __restrict__ env_ws,
    float* __restrict__ out) {
  __shared__ float2 zs[4 * ZROW];
  __shared__ float2 tws[64];
  __shared__ float  nf_s[64];
  __shared__ int    rowk1[4];
  int b = blockIdx.x, t = blockIdx.y, tid = threadIdx.x;
  tw_init(tws, tid);
  if (tid >= 64 && tid < 128) nf_s[tid - 64] = packed[b * 480 + 416 + (tid - 64)];
  if (tid < 4) {
    int s = tid & 1;
    int m = t * 2 + s;
    rowk1[tid] = (tid < 2) ? m : ((m == 0) ? 64 : 128 - m);
  }
  __syncthreads();
  float2* Ab = A + (size_t)b * MFFT;

  #pragma unroll
  for (int it = 0; it < 4; ++it) {
    int e = it * 128 + tid;
    int r = e >> 7, n2 = e & 127;
    zs[zp(r, brev7(n2))] = Ab[rowk1[r] * 128 + n2];
  }
  __syncthreads();
  fft128_r4<false>(zs, tws, tid);   // zs[zp(r,k2)] = Z[rowk1[r] + 128*k2]

  const float hsc = 1.0f / 16384.0f;
  #pragma unroll
  for (int it = 0; it < 2; ++it) {
    int task = it * 128 + tid;      // 256 tasks: (local row r, k2 in 0..63)
    int r  = task >> 6;
    int k2 = task & 63;
    int k1 = rowk1[r];
    int f = k1 + (k2 << 7);
    if (f == 0) {                   // DC and f=8192 specials (WG t=0 only)
      float2 Z0 = zs[zp(0, 0)];
      float X0 = Z0.x + Z0.y;
      float Y0 = X0 * (h_filter(0, nf_s) * hsc);
      zs[zp(0, 0)] = make_float2(0.5f * Y0, 0.5f * Y0);   // H[M]=0 -> YM=0
      float Hm = h_filter(8192, nf_s) * hsc;
      float2 Zm = zs[zp(0, 64)];
      zs[zp(0, 64)] = make_float2(Zm.x * Hm, Zm.y * Hm);
    } else {
      int g = 16384 - f;
      int k1g = g & 127;
      int pr = (k1g == k1) ? r : ((r < 2) ? r + 2 : r - 2);
      int k2p = g >> 7;
      float2 Zf = zs[zp(r, k2)], Zg = zs[zp(pr, k2p)];
      float Ax = 0.5f * (Zf.x + Zg.x), Ay = 0.5f * (Zf.y - Zg.y);
      float Bx = 0.5f * (Zf.x - Zg.x), By = 0.5f * (Zf.y + Zg.y);
      float ang = (-(float)M_PI / (float)MFFT) * (float)f;
      float ss, cc; __sincosf(ang, &ss, &cc);
      float WBx = cc * Bx - ss * By, WBy = cc * By + ss * Bx;
      float Hf = h_filter(f, nf_s) * hsc;
      float Hg = h_filter(g, nf_s) * hsc;
      float Yfx = (Ax + WBy) * Hf, Yfy = (Ay - WBx) * Hf;
      float Ygx = (Ax - WBy) * Hg, Ygy = (-Ay - WBx) * Hg;
      float A2x = 0.5f * (Yfx + Ygx), A2y = 0.5f * (Yfy - Ygy);
      float B2x = 0.5f * (Yfx - Ygx), B2y = 0.5f * (Yfy + Ygy);
      float CBx = cc * B2x + ss * B2y;
      float CBy = cc * B2y - ss * B2x;
      zs[zp(r, k2)]   = make_float2(A2x - CBy, A2y + CBx);
      float DBx = cc * B2x + ss * B2y;
      float DBy = ss * B2x - cc * B2y;
      zs[zp(pr, k2p)] = make_float2(A2x - DBy, -A2y + DBx);
    }
  }
  __syncthreads();

  fft128_r4_dif_inv(zs, tws, tid);  // natural -> bitrev

  #pragma unroll
  for (int it = 0; it < 4; ++it) {
    int e = it * 128 + tid;
    int r = e >> 7, n2 = e & 127;
    int k1 = rowk1[r];
    float2 v = zs[zp(r, brev7(n2))];
    float ang = (2.0f * (float)M_PI / 16384.0f) * (float)(k1 * n2);
    float ss, cc; __sincosf(ang, &ss, &cc);
    Ab[k1 * 128 + n2] = make_float2(cc * v.x - ss * v.y, cc * v.y + ss * v.x);
  }

  // ---- independent oscillator-bank slice (16 samples per WG) ----
  {
    __shared__ float oscs[16];
    const double TWO_PI     = 6.283185307179586476925286766559;
    const double INV_TWO_PI = 0.15915494309189533576888376337251;
    int gid = b * 32 + t;              // 0..2047
    int lane = tid & 63;               // channel-batch
    int w = tid >> 6;                  // wave: 8 samples each
    int chunk = gid >> 3, sub = gid & 7;
    int s0 = chunk * 128 + sub * 16;
    int K = chunk >> 1, half = chunk & 1;

    double r0 = r64_ws[lane * 16];     // fundamental step angle (f64)
    double rr = r0 - rint(r0 * INV_TWO_PI) * TWO_PI;
    double x0 = (double)(s0 + w * 8 + 1) * r0;
    double ph = x0 - rint(x0 * INV_TWO_PI) * TWO_PI;
    float s1, c1, srot, crot;
    __sincosf((float)ph, &s1, &c1);
    __sincosf((float)rr, &srot, &crot);

    int km1 = (K > 0) ? (K - 1) : 0;
    int kp1 = (K < 127) ? (K + 1) : 127;
    int fA = half ? K : km1;
    int fB = half ? kp1 : K;
    const float4* eA = (const float4*)(env_ws + fA * 1024 + lane * 16);
    const float4* eB = (const float4*)(env_ws + fB * 1024 + lane * 16);
    float ev[16], sl[16];
    float basew = (half ? 0.5f : 128.5f) + (float)(sub * 16 + w * 8);
    #pragma unroll
    for (int q = 0; q < 4; ++q) {
      float4 a = eA[q], bb = eB[q];
      float d;
      d = (bb.x - a.x) * (1.0f / 256.0f); sl[q*4+0] = d; ev[q*4+0] = a.x + d * basew;
      d = (bb.y - a.y) * (1.0f / 256.0f); sl[q*4+1] = d; ev[q*4+1] = a.y + d * basew;
      d = (bb.z - a.z) * (1.0f / 256.0f); sl[q*4+2] = d; ev[q*4+2] = a.z + d * basew;
      d = (bb.w - a.w) * (1.0f / 256.0f); sl[q*4+3] = d; ev[q*4+3] = a.w + d * basew;
    }

    #pragma unroll
    for (int j = 0; j < 8; ++j) {
      float twoC = c1 + c1;
      float sm1 = 0.0f, sc = s1;
      float acc = ev[0] * sc; ev[0] += sl[0];
      #pragma unroll
      for (int i = 1; i < 16; ++i) {
        float sn = fmaf(twoC, sc, -sm1);
        sm1 = sc; sc = sn;
        acc = fmaf(ev[i], sn, acc);
        ev[i] += sl[i];
      }
      acc += __shfl_xor(acc, 32);
      acc += __shfl_xor(acc, 16);
      acc += __shfl_xor(acc, 8);
      acc += __shfl_xor(acc, 4);
      acc += __shfl_xor(acc, 2);
      acc += __shfl_xor(acc, 1);
      if (lane == 0) oscs[w * 8 + j] = acc;
      float tn = fmaf(s1, crot, c1 * srot);      // uses old s1,c1
      c1 = fmaf(c1, crot, -(s1 * srot));
      s1 = tn;
    }
    __syncthreads();
    if (tid < 16) out[s0 + tid] = oscs[tid] * (1.0f / 1024.0f);
  }
}

// ---------------------------------------------------------------------------
// kernel 3 -- ki2: column inverse FFTs (over k1) + amp*clip -> ws2
// (plain coalesced stores; no atomics). grid (BATCH, 32) x 128.
// ---------------------------------------------------------------------------
__global__ __launch_bounds__(128, 4) void ki2(
    const float* __restrict__ packed, const float2* __restrict__ A,
    float2* __restrict__ ws2) {
  __shared__ float2 zs[4 * ZROW];
  __shared__ float2 tws[64];
  __shared__ float amp_s[128];
  int b = blockIdx.x, tile = blockIdx.y, tid = threadIdx.x;
  tw_init(tws, tid);
  amp_s[tid] = packed[b * 480 + 256 + tid] * 2.0f - 1.0f;
  const float2* Ab = A + (size_t)b * MFFT;
  #pragma unroll
  for (int it = 0; it < 4; ++it) {
    int e = it * 128 + tid;
    int k1 = e >> 2, n2l = e & 3;
    zs[zp(n2l, brev7(k1))] = Ab[k1 * 128 + tile * 4 + n2l];
  }
  __syncthreads();
  fft128_r4<true>(zs, tws, tid);
  float2* W2 = ws2 + (size_t)b * MFFT;
  #pragma unroll
  for (int it = 0; it < 4; ++it) {
    int e = it * 128 + tid;
    int n1 = e >> 2, n2l = e & 3;
    int n2 = tile * 4 + n2l;
    int n = n1 * 128 + n2;
    float2 v = zs[zp(n2l, n1)];
    v.x *= amp_lerp(2 * n,     amp_s);
    v.y *= amp_lerp(2 * n + 1, amp_s);
    W2[n] = v;
  }
}

// ---------------------------------------------------------------------------
// kernel 4 -- kd: batch-mean of noise, thread-per-sample (exclusive owner,
// no atomics): out[s] += (1/64) * sum_b ws2[b][s]. grid 256 x 128.
// Reads coalesced across lanes; 64 independent strided loads per thread.
// ---------------------------------------------------------------------------
__global__ __launch_bounds__(128) void kd(
    const float* __restrict__ ws2f, float* __restrict__ out) {
  int s = blockIdx.x * 128 + threadIdx.x;        // 0..32767
  const float* src = ws2f + s;
  float acc = 0.0f;
  #pragma unroll
  for (int b = 0; b < BATCH; ++b) acc += src[(size_t)b * NSAMP];
  out[s] += acc * (1.0f / 64.0f);
}

// ---------------------------------------------------------------------------
extern "C" void kernel_launch(void* const* d_in, const int* in_sizes, int n_in,
                              void* d_out, int out_size, void* d_ws, size_t ws_size,
                              hipStream_t stream) {
  const float* packed  = (const float*)d_in[0];
  const float* gumbel  = (const float*)d_in[1];
  const float* noise_u = (const float*)d_in[2];
  float* out = (float*)d_out;

  // ws layout: [r64 8KB][env 512KB][A 8MB][ws2 8MB]
  char* wsc = (char*)d_ws;
  double* r64_ws = (double*)wsc;
  float*  env_ws = (float*)(wsc + 8192);
  float2* A      = (float2*)(wsc + 8192 + 524288);
  float2* ws2    = (float2*)(wsc + 8192 + 524288 + (size_t)BATCH * MFFT * 8);

  kf1 <<<dim3(BATCH, 33), 128, 0, stream>>>(noise_u, A, packed, gumbel, r64_ws, env_ws);
  kmid<<<dim3(BATCH, 32), 128, 0, stream>>>(packed, A, r64_ws, env_ws, out);
  ki2 <<<dim3(BATCH, 32), 128, 0, stream>>>(packed, A, ws2);
  kd  <<<256, 128, 0, stream>>>((const float*)ws2, out);
}

// Round 15
// 38.613 us; speedup vs baseline: 1.7241x; 1.3799x over previous
//
#include <hip/hip_runtime.h>
#include <math.h>

#define NSAMP   32768
#define NFRAMES 128
#define NHARM   16
#define BATCH   64
#define MFFT    16384          // complex FFT size (even/odd real pack), = 128*128
#define ZROW    137            // LDS row stride (float2) per 128-entry FFT row

static __device__ __forceinline__ float clampf(float x, float lo, float hi) {
  return fminf(fmaxf(x, lo), hi);
}
static __device__ __forceinline__ int zp(int fft, int p) {        // LDS swizzle
  return fft * ZROW + p + (p >> 4);
}
static __device__ __forceinline__ int brev7(int n) {
  return (int)(__brev((unsigned)n) >> 25);
}
static __device__ __forceinline__ float2 cmulf(float c, float s, float2 v) {
  return make_float2(c * v.x - s * v.y, c * v.y + s * v.x);
}
static __device__ __forceinline__ float2 f2add(float2 a, float2 b) {
  return make_float2(a.x + b.x, a.y + b.y);
}
static __device__ __forceinline__ float2 f2sub(float2 a, float2 b) {
  return make_float2(a.x - b.x, a.y - b.y);
}

static __device__ __forceinline__ void tw_init(float2* tws, int tid) {
  if (tid < 64) {
    float s, c;
    __sincosf(-(float)M_PI * (float)tid * (1.0f / 64.0f), &s, &c);
    tws[tid] = make_float2(c, s);
  }
}

// ---------------------------------------------------------------------------
// NT/32 FFTs of length 128 in LDS, NT threads, radix-4 fused stage-pairs
// (3 radix-4 + 1 radix-2). DIT: bit-reversed input -> natural output.
// tws[j] = e^{-i pi j/64}; INV conjugates; w2b = (fwd) -i*w2a / (inv) +i*w2a.
// With NT=64 the WG is a single wave: all __syncthreads are hardware-free.
// ---------------------------------------------------------------------------
template <int NT, bool INV>
static __device__ __forceinline__ void fft128_r4(float2* zs, const float2* tws, int tid) {
  constexpr int NF = NT / 32;
  int fft = tid >> 5, i = tid & 31;
  #pragma unroll
  for (int s = 0; s < 6; s += 2) {
    int half = 1 << s;
    int kk1 = i & (half - 1);
    int base = ((i & ~(half - 1)) << 2) | kk1;
    int p0 = zp(fft, base),            p1 = zp(fft, base + half);
    int p2 = zp(fft, base + 2 * half), p3 = zp(fft, base + 3 * half);
    float2 q0 = zs[p0], q1 = zs[p1], q2 = zs[p2], q3 = zs[p3];
    float2 t1 = tws[kk1 << (6 - s)], t2 = tws[kk1 << (5 - s)];
    float c1 = t1.x, s1 = INV ? -t1.y : t1.y;
    float c2 = t2.x, s2 = INV ? -t2.y : t2.y;
    float c2b = INV ? -s2 : s2, s2b = INV ? c2 : -c2;
    float2 t;
    t = cmulf(c1, s1, q1);   float2 A0 = f2add(q0, t), A1 = f2sub(q0, t);
    t = cmulf(c1, s1, q3);   float2 A2 = f2add(q2, t), A3 = f2sub(q2, t);
    t = cmulf(c2, s2, A2);   zs[p0] = f2add(A0, t); zs[p2] = f2sub(A0, t);
    t = cmulf(c2b, s2b, A3); zs[p1] = f2add(A1, t); zs[p3] = f2sub(A1, t);
    __syncthreads();
  }
  #pragma unroll
  for (int j = tid; j < NF * 64; j += NT) {        // stage 6, radix-2
    int f = j >> 6, kk = j & 63;
    float2 w = tws[kk];
    float cc = w.x, ss = INV ? -w.y : w.y;
    int a0 = zp(f, kk), a1 = zp(f, kk + 64);
    float2 a = zs[a0], bv = zs[a1];
    float2 t = cmulf(cc, ss, bv);
    zs[a0] = f2add(a, t); zs[a1] = f2sub(a, t);
  }
  __syncthreads();
}

// Inverse as DIF: natural input -> bit-reversed output. Stage 6 first, then
// fused pairs (5,4),(3,2),(1,0). Twiddles conjugated; w2b = +i*w2a.
template <int NT>
static __device__ __forceinline__ void fft128_r4_dif_inv(float2* zs, const float2* tws, int tid) {
  constexpr int NF = NT / 32;
  #pragma unroll
  for (int j = tid; j < NF * 64; j += NT) {        // stage 6, radix-2 DIF
    int f = j >> 6, kk = j & 63;
    float2 w = tws[kk];
    float cc = w.x, ss = -w.y;
    int a0 = zp(f, kk), a1 = zp(f, kk + 64);
    float2 u = zs[a0], v = zs[a1];
    zs[a0] = f2add(u, v);
    zs[a1] = cmulf(cc, ss, f2sub(u, v));
  }
  __syncthreads();
  int fft = tid >> 5, i = tid & 31;
  #pragma unroll
  for (int s = 4; s >= 0; s -= 2) {
    int half = 1 << s;
    int kk1 = i & (half - 1);
    int base = ((i & ~(half - 1)) << 2) | kk1;
    int p0 = zp(fft, base),            p1 = zp(fft, base + half);
    int p2 = zp(fft, base + 2 * half), p3 = zp(fft, base + 3 * half);
    float2 q0 = zs[p0], q1 = zs[p1], q2 = zs[p2], q3 = zs[p3];
    float2 t1 = tws[kk1 << (6 - s)], t2 = tws[kk1 << (5 - s)];
    float c1 = t1.x, s1 = -t1.y;
    float c2 = t2.x, s2 = -t2.y;
    float c2b = -s2, s2b = c2;                  // +i * (c2, s2)
    float2 B0 = f2add(q0, q2);
    float2 B2 = cmulf(c2, s2, f2sub(q0, q2));
    float2 B1 = f2add(q1, q3);
    float2 B3 = cmulf(c2b, s2b, f2sub(q1, q3));
    zs[p0] = f2add(B0, B1);
    zs[p1] = cmulf(c1, s1, f2sub(B0, B1));
    zs[p2] = f2add(B2, B3);
    zs[p3] = cmulf(c1, s1, f2sub(B2, B3));
    __syncthreads();
  }
}

static __device__ __forceinline__ float h_filter(int f, const float* nf_s) {
  float coords = ((float)f + 0.5f) * (1.0f / 256.0f) - 0.5f;
  coords = clampf(coords, 0.0f, 63.0f);
  int i0 = (int)coords;
  int i1 = (i0 < 63) ? (i0 + 1) : 63;
  float w = coords - (float)i0;
  return nf_s[i0] * (1.0f - w) + nf_s[i1] * w;
}

static __device__ __forceinline__ float amp_lerp(int s, const float* amp_s) {
  float coords = ((float)s + 0.5f) * (1.0f / 256.0f) - 0.5f;
  coords = clampf(coords, 0.0f, 127.0f);
  int i0 = (int)coords;
  int i1 = (i0 < 127) ? (i0 + 1) : 127;
  float w = coords - (float)i0;
  float v = amp_s[i0] * (1.0f - w) + amp_s[i1] * w;
  return clampf(v, 0.0f, 1.0f);
}

// ---------------------------------------------------------------------------
// k1 body (kf1's blockIdx.y==0 slice, 64 threads): gumbel argmax -> f0 ->
// radians (f64); 128-frame env scan. env layout: env_ws[frame*1024 + channel]
// ---------------------------------------------------------------------------
static __device__ void k1_body(
    const float* __restrict__ packed, const float* __restrict__ gumbel,
    double* __restrict__ r64_ws, float* __restrict__ env_ws, int b, int tid) {
  __shared__ double zv[128];
  __shared__ int    zi[128];
  __shared__ double f0_sh;
  const float* pk = packed + b * 480;

  #pragma unroll
  for (int q = 0; q < 2; ++q) {
    int idx = tid + q * 64;
    double u = (double)gumbel[b * 128 + idx];
    double t = -log(u + 1e-10);
    double g = -log(t + 1e-10);
    zv[idx] = (double)pk[idx] + g;
    zi[idx] = idx;
  }
  __syncthreads();
  for (int s = 64; s > 0; s >>= 1) {
    if (tid < s) {
      double a = zv[tid], c = zv[tid + s];
      int ia = zi[tid], ic = zi[tid + s];
      if (c > a || (c == a && ic < ia)) { zv[tid] = c; zi[tid] = ic; }
    }
    __syncthreads();
  }
  if (tid == 0) {
    int note = zi[0];
    double Fd  = 440.0 * exp2(((double)(note - 69)) / 12.0) / 11025.0;
    float  F32 = (float)Fd;                     // FREQS is f32 in the reference
    double f0  = (double)F32 * 11025.0;
    f0 = (40.0 / 11025.0) + f0 * (3000.0 / 11025.0 - 40.0 / 11025.0);
    f0_sh = f0;
  }
  __syncthreads();
  if (tid < NHARM) {
    int h = tid;
    int c = b * NHARM + h;
    const float PIF = 3.14159265358979323846f;  // float32(np.pi)
    double osc = f0_sh * (double)(h + 1);
    r64_ws[c] = (osc / 11025.0) * (double)PIF;
    float ha = pk[384 + h];
    float hd = 0.1f + pk[400 + h] * 0.9f;
    float cur = 0.0f;
    for (int tt = 0; tt < NFRAMES; ++tt) {
      float a = pk[256 + tt] * 2.0f - 1.0f;
      cur = clampf(cur + a * ha, 0.0f, 1.0f);
      env_ws[tt * 1024 + c] = cur;
      cur = cur * hd;
    }
  }
}

// ---------------------------------------------------------------------------
// kernel 1 -- kf1: column FFTs (length 128 over n1) + W_M^{n2 k1} twiddle;
// blockIdx.y==0 runs k1. grid (BATCH, 65) x 64; 2 columns per FFT WG.
// ---------------------------------------------------------------------------
__global__ __launch_bounds__(64, 4) void kf1(
    const float* __restrict__ noise_u, float2* __restrict__ A,
    const float* __restrict__ packed, const float* __restrict__ gumbel,
    double* __restrict__ r64_ws, float* __restrict__ env_ws) {
  int b = blockIdx.x, tid = threadIdx.x;
  if (blockIdx.y == 0) { k1_body(packed, gumbel, r64_ws, env_ws, b, tid); return; }
  int tile = blockIdx.y - 1;          // 0..63
  __shared__ float2 zs[2 * ZROW];
  __shared__ float2 tws[64];
  tw_init(tws, tid);
  const float2* nu2 = (const float2*)(noise_u + (size_t)b * NSAMP);
  #pragma unroll
  for (int it = 0; it < 4; ++it) {
    int e = it * 64 + tid;
    int n1 = e >> 1, n2l = e & 1;
    float2 xv = nu2[n1 * 128 + tile * 2 + n2l];
    zs[zp(n2l, brev7(n1))] = make_float2(xv.x * 2.0f - 1.0f, xv.y * 2.0f - 1.0f);
  }
  __syncthreads();
  fft128_r4<64, false>(zs, tws, tid);
  float2* Ab = A + (size_t)b * MFFT;
  #pragma unroll
  for (int it = 0; it < 4; ++it) {
    int e = it * 64 + tid;
    int k1 = e >> 1, n2l = e & 1;
    int n2 = tile * 2 + n2l;
    float2 v = zs[zp(n2l, k1)];
    float ang = -(2.0f * (float)M_PI / 16384.0f) * (float)(k1 * n2);
    float ss, cc; __sincosf(ang, &ss, &cc);
    Ab[k1 * 128 + n2] = make_float2(cc * v.x - ss * v.y, cc * v.y + ss * v.x);
  }
}

// ---------------------------------------------------------------------------
// kernel 2 -- kmid: fused row-FFT (fwd) -> Hermitian filter (LDS) ->
// row-IFFT (DIF) -> conj twiddle. 2 rows = 1 pair-group per WG:
// rows {t, 128-t}; t=0 -> {0, 64} (self-paired rows). grid (BATCH, 64) x 64.
// ---------------------------------------------------------------------------
__global__ __launch_bounds__(64, 4) void kmid(
    const float* __restrict__ packed, float2* __restrict__ A) {
  __shared__ float2 zs[2 * ZROW];
  __shared__ float2 tws[64];
  __shared__ float  nf_s[64];
  __shared__ int    rowk1[2];
  int b = blockIdx.x, t = blockIdx.y, tid = threadIdx.x;
  tw_init(tws, tid);
  nf_s[tid] = packed[b * 480 + 416 + tid];
  if (tid < 2)
    rowk1[tid] = (tid == 0) ? t : ((t == 0) ? 64 : 128 - t);
  __syncthreads();
  float2* Ab = A + (size_t)b * MFFT;

  #pragma unroll
  for (int it = 0; it < 4; ++it) {
    int e = it * 64 + tid;
    int r = e >> 7, n2 = e & 127;
    zs[zp(r, brev7(n2))] = Ab[rowk1[r] * 128 + n2];
  }
  __syncthreads();
  fft128_r4<64, false>(zs, tws, tid);   // zs[zp(r,k2)] = Z[rowk1[r] + 128*k2]

  const float hsc = 1.0f / 16384.0f;
  #pragma unroll
  for (int it = 0; it < 2; ++it) {
    int task = it * 64 + tid;      // 128 tasks: (local row r, k2 in 0..63)
    int r  = task >> 6;
    int k2 = task & 63;
    int k1 = rowk1[r];
    int f = k1 + (k2 << 7);
    if (f == 0) {                   // DC and f=8192 specials (WG t=0 only)
      float2 Z0 = zs[zp(0, 0)];
      float X0 = Z0.x + Z0.y;
      float Y0 = X0 * (h_filter(0, nf_s) * hsc);
      zs[zp(0, 0)] = make_float2(0.5f * Y0, 0.5f * Y0);   // H[M]=0 -> YM=0
      float Hm = h_filter(8192, nf_s) * hsc;
      float2 Zm = zs[zp(0, 64)];
      zs[zp(0, 64)] = make_float2(Zm.x * Hm, Zm.y * Hm);
    } else {
      int g = 16384 - f;
      int k1g = g & 127;
      int pr = (k1g == k1) ? r : (r ^ 1);
      int k2p = g >> 7;
      float2 Zf = zs[zp(r, k2)], Zg = zs[zp(pr, k2p)];
      float Ax = 0.5f * (Zf.x + Zg.x), Ay = 0.5f * (Zf.y - Zg.y);
      float Bx = 0.5f * (Zf.x - Zg.x), By = 0.5f * (Zf.y + Zg.y);
      float ang = (-(float)M_PI / (float)MFFT) * (float)f;
      float ss, cc; __sincosf(ang, &ss, &cc);
      float WBx = cc * Bx - ss * By, WBy = cc * By + ss * Bx;
      float Hf = h_filter(f, nf_s) * hsc;
      float Hg = h_filter(g, nf_s) * hsc;
      float Yfx = (Ax + WBy) * Hf, Yfy = (Ay - WBx) * Hf;
      float Ygx = (Ax - WBy) * Hg, Ygy = (-Ay - WBx) * Hg;
      float A2x = 0.5f * (Yfx + Ygx), A2y = 0.5f * (Yfy - Ygy);
      float B2x = 0.5f * (Yfx - Ygx), B2y = 0.5f * (Yfy + Ygy);
      float CBx = cc * B2x + ss * B2y;
      float CBy = cc * B2y - ss * B2x;
      zs[zp(r, k2)]   = make_float2(A2x - CBy, A2y + CBx);
      float DBx = cc * B2x + ss * B2y;
      float DBy = ss * B2x - cc * B2y;
      zs[zp(pr, k2p)] = make_float2(A2x - DBy, -A2y + DBx);
    }
  }
  __syncthreads();

  fft128_r4_dif_inv<64>(zs, tws, tid);  // natural -> bitrev

  #pragma unroll
  for (int it = 0; it < 4; ++it) {
    int e = it * 64 + tid;
    int r = e >> 7, n2 = e & 127;
    int k1 = rowk1[r];
    float2 v = zs[zp(r, brev7(n2))];
    float ang = (2.0f * (float)M_PI / 16384.0f) * (float)(k1 * n2);
    float ss, cc; __sincosf(ang, &ss, &cc);
    Ab[k1 * 128 + n2] = make_float2(cc * v.x - ss * v.y, cc * v.y + ss * v.x);
  }
}

// ---------------------------------------------------------------------------
// kernel 3 -- ki2: column inverse FFTs (over k1) + amp*clip -> ws2
// (plain coalesced stores). grid (BATCH, 64) x 64; 2 columns per WG.
// ---------------------------------------------------------------------------
__global__ __launch_bounds__(64, 4) void ki2(
    const float* __restrict__ packed, const float2* __restrict__ A,
    float2* __restrict__ ws2) {
  __shared__ float2 zs[2 * ZROW];
  __shared__ float2 tws[64];
  __shared__ float amp_s[128];
  int b = blockIdx.x, tile = blockIdx.y, tid = threadIdx.x;
  tw_init(tws, tid);
  amp_s[tid]      = packed[b * 480 + 256 + tid] * 2.0f - 1.0f;
  amp_s[tid + 64] = packed[b * 480 + 256 + tid + 64] * 2.0f - 1.0f;
  const float2* Ab = A + (size_t)b * MFFT;
  #pragma unroll
  for (int it = 0; it < 4; ++it) {
    int e = it * 64 + tid;
    int k1 = e >> 1, n2l = e & 1;
    zs[zp(n2l, brev7(k1))] = Ab[k1 * 128 + tile * 2 + n2l];
  }
  __syncthreads();
  fft128_r4<64, true>(zs, tws, tid);
  float2* W2 = ws2 + (size_t)b * MFFT;
  #pragma unroll
  for (int it = 0; it < 4; ++it) {
    int e = it * 64 + tid;
    int n1 = e >> 1, n2l = e & 1;
    int n2 = tile * 2 + n2l;
    int n = n1 * 128 + n2;
    float2 v = zs[zp(n2l, n1)];
    v.x *= amp_lerp(2 * n,     amp_s);
    v.y *= amp_lerp(2 * n + 1, amp_s);
    W2[n] = v;
  }
}

// ---------------------------------------------------------------------------
// kernel 4 -- k3r: oscillator bank (Chebyshev harmonic recurrence) +
// batch-mean of noise, fused (R7-proven). 256 WGs x 1024 thr; WG k covers
// 128 samples; wave lane = batch channel. Plain stores (covers out once).
// ---------------------------------------------------------------------------
__global__ __launch_bounds__(1024) void k3r(
    const double* __restrict__ r64_ws, const float* __restrict__ env_ws,
    const float* __restrict__ ws2f, float* __restrict__ out) {
  __shared__ float oscs[128];
  __shared__ float nse[8][128];
  const double TWO_PI     = 6.283185307179586476925286766559;
  const double INV_TWO_PI = 0.15915494309189533576888376337251;
  int tid = threadIdx.x;
  int lane = tid & 63;               // batch
  int wv = tid >> 6;                 // sample group (0..15), 8 samples each
  int k = blockIdx.x;                // 128-sample chunk
  int s0 = k * 128;
  int K = k >> 1, half = k & 1;

  double r0 = r64_ws[lane * 16];     // fundamental step angle (f64)
  double rr = r0 - rint(r0 * INV_TWO_PI) * TWO_PI;
  double x0 = (double)(s0 + wv * 8 + 1) * r0;
  double ph = x0 - rint(x0 * INV_TWO_PI) * TWO_PI;
  float s1, c1, srot, crot;
  __sincosf((float)ph, &s1, &c1);
  __sincosf((float)rr, &srot, &crot);

  int km1 = (K > 0) ? (K - 1) : 0;
  int kp1 = (K < 127) ? (K + 1) : 127;
  int fA = half ? K : km1;
  int fB = half ? kp1 : K;
  const float4* eA = (const float4*)(env_ws + fA * 1024 + lane * 16);
  const float4* eB = (const float4*)(env_ws + fB * 1024 + lane * 16);
  float ev[16], sl[16];
  float basew = (half ? 0.5f : 128.5f) + (float)(wv * 8);
  #pragma unroll
  for (int q = 0; q < 4; ++q) {
    float4 a = eA[q], bb = eB[q];
    float d;
    d = (bb.x - a.x) * (1.0f / 256.0f); sl[q*4+0] = d; ev[q*4+0] = a.x + d * basew;
    d = (bb.y - a.y) * (1.0f / 256.0f); sl[q*4+1] = d; ev[q*4+1] = a.y + d * basew;
    d = (bb.z - a.z) * (1.0f / 256.0f); sl[q*4+2] = d; ev[q*4+2] = a.z + d * basew;
    d = (bb.w - a.w) * (1.0f / 256.0f); sl[q*4+3] = d; ev[q*4+3] = a.w + d * basew;
  }

  #pragma unroll
  for (int j = 0; j < 8; ++j) {
    float twoC = c1 + c1;
    float sm1 = 0.0f, sc = s1;
    float acc = ev[0] * sc; ev[0] += sl[0];
    #pragma unroll
    for (int i = 1; i < 16; ++i) {
      float sn = fmaf(twoC, sc, -sm1);
      sm1 = sc; sc = sn;
      acc = fmaf(ev[i], sn, acc);
      ev[i] += sl[i];
    }
    acc += __shfl_xor(acc, 32);
    acc += __shfl_xor(acc, 16);
    acc += __shfl_xor(acc, 8);
    acc += __shfl_xor(acc, 4);
    acc += __shfl_xor(acc, 2);
    acc += __shfl_xor(acc, 1);
    if (lane == 0) oscs[wv * 8 + j] = acc;
    float tn = fmaf(s1, crot, c1 * srot);      // uses old s1,c1
    c1 = fmaf(c1, crot, -(s1 * srot));
    s1 = tn;
  }
  __syncthreads();

  // batch-mean of noise: 8 groups x 8 batches each, coalesced rows
  {
    int j = tid & 127, grp = tid >> 7;
    const float* src = ws2f + (size_t)(grp * 8) * NSAMP + s0 + j;
    float acc = 0.0f;
    #pragma unroll
    for (int bb = 0; bb < 8; ++bb) acc += src[(size_t)bb * NSAMP];
    nse[grp][j] = acc;
  }
  __syncthreads();

  if (tid < 128) {
    float nz = 0.0f;
    #pragma unroll
    for (int g = 0; g < 8; ++g) nz += nse[g][tid];
    out[s0 + tid] = oscs[tid] * (1.0f / 1024.0f) + nz * (1.0f / 64.0f);
  }
}

// ---------------------------------------------------------------------------
extern "C" void kernel_launch(void* const* d_in, const int* in_sizes, int n_in,
                              void* d_out, int out_size, void* d_ws, size_t ws_size,
                              hipStream_t stream) {
  const float* packed  = (const float*)d_in[0];
  const float* gumbel  = (const float*)d_in[1];
  const float* noise_u = (const float*)d_in[2];
  float* out = (float*)d_out;

  // ws layout: [r64 8KB][env 512KB][A 8MB][ws2 8MB]
  char* wsc = (char*)d_ws;
  double* r64_ws = (double*)wsc;
  float*  env_ws = (float*)(wsc + 8192);
  float2* A      = (float2*)(wsc + 8192 + 524288);
  float2* ws2    = (float2*)(wsc + 8192 + 524288 + (size_t)BATCH * MFFT * 8);

  kf1 <<<dim3(BATCH, 65), 64, 0, stream>>>(noise_u, A, packed, gumbel, r64_ws, env_ws);
  kmid<<<dim3(BATCH, 64), 64, 0, stream>>>(packed, A);
  ki2 <<<dim3(BATCH, 64), 64, 0, stream>>>(packed, A, ws2);
  k3r <<<256, 1024, 0, stream>>>(r64_ws, env_ws, (const float*)ws2, out);
}

// Round 16
// 37.593 us; speedup vs baseline: 1.7709x; 1.0271x over previous
//
#include <hip/hip_runtime.h>
#include <math.h>

#define NSAMP   32768
#define NFRAMES 128
#define NHARM   16
#define BATCH   64
#define MFFT    16384          // complex FFT size (even/odd real pack), = 128*128
#define ZROW    137            // LDS row stride (float2) per 128-entry FFT row

static __device__ __forceinline__ float clampf(float x, float lo, float hi) {
  return fminf(fmaxf(x, lo), hi);
}
static __device__ __forceinline__ int zp(int fft, int p) {        // LDS swizzle
  return fft * ZROW + p + (p >> 4);
}
static __device__ __forceinline__ int brev7(int n) {
  return (int)(__brev((unsigned)n) >> 25);
}
static __device__ __forceinline__ float2 cmulf(float c, float s, float2 v) {
  return make_float2(c * v.x - s * v.y, c * v.y + s * v.x);
}
static __device__ __forceinline__ float2 f2add(float2 a, float2 b) {
  return make_float2(a.x + b.x, a.y + b.y);
}
static __device__ __forceinline__ float2 f2sub(float2 a, float2 b) {
  return make_float2(a.x - b.x, a.y - b.y);
}

static __device__ __forceinline__ void tw_init(float2* tws, int tid) {
  if (tid < 64) {
    float s, c;
    __sincosf(-(float)M_PI * (float)tid * (1.0f / 64.0f), &s, &c);
    tws[tid] = make_float2(c, s);
  }
}

// ---------------------------------------------------------------------------
// NT/32 FFTs of length 128 in LDS, NT threads, radix-4 fused stage-pairs
// (3 radix-4 + 1 radix-2). DIT: bit-reversed input -> natural output.
// tws[j] = e^{-i pi j/64}; INV conjugates; w2b = (fwd) -i*w2a / (inv) +i*w2a.
// ---------------------------------------------------------------------------
template <int NT, bool INV>
static __device__ __forceinline__ void fft128_r4(float2* zs, const float2* tws, int tid) {
  constexpr int NF = NT / 32;
  int fft = tid >> 5, i = tid & 31;
  #pragma unroll
  for (int s = 0; s < 6; s += 2) {
    int half = 1 << s;
    int kk1 = i & (half - 1);
    int base = ((i & ~(half - 1)) << 2) | kk1;
    int p0 = zp(fft, base),            p1 = zp(fft, base + half);
    int p2 = zp(fft, base + 2 * half), p3 = zp(fft, base + 3 * half);
    float2 q0 = zs[p0], q1 = zs[p1], q2 = zs[p2], q3 = zs[p3];
    float2 t1 = tws[kk1 << (6 - s)], t2 = tws[kk1 << (5 - s)];
    float c1 = t1.x, s1 = INV ? -t1.y : t1.y;
    float c2 = t2.x, s2 = INV ? -t2.y : t2.y;
    float c2b = INV ? -s2 : s2, s2b = INV ? c2 : -c2;
    float2 t;
    t = cmulf(c1, s1, q1);   float2 A0 = f2add(q0, t), A1 = f2sub(q0, t);
    t = cmulf(c1, s1, q3);   float2 A2 = f2add(q2, t), A3 = f2sub(q2, t);
    t = cmulf(c2, s2, A2);   zs[p0] = f2add(A0, t); zs[p2] = f2sub(A0, t);
    t = cmulf(c2b, s2b, A3); zs[p1] = f2add(A1, t); zs[p3] = f2sub(A1, t);
    __syncthreads();
  }
  #pragma unroll
  for (int j = tid; j < NF * 64; j += NT) {        // stage 6, radix-2
    int f = j >> 6, kk = j & 63;
    float2 w = tws[kk];
    float cc = w.x, ss = INV ? -w.y : w.y;
    int a0 = zp(f, kk), a1 = zp(f, kk + 64);
    float2 a = zs[a0], bv = zs[a1];
    float2 t = cmulf(cc, ss, bv);
    zs[a0] = f2add(a, t); zs[a1] = f2sub(a, t);
  }
  __syncthreads();
}

// Inverse as DIF: natural input -> bit-reversed output. Stage 6 first, then
// fused pairs (5,4),(3,2),(1,0). Twiddles conjugated; w2b = +i*w2a.
template <int NT>
static __device__ __forceinline__ void fft128_r4_dif_inv(float2* zs, const float2* tws, int tid) {
  constexpr int NF = NT / 32;
  #pragma unroll
  for (int j = tid; j < NF * 64; j += NT) {        // stage 6, radix-2 DIF
    int f = j >> 6, kk = j & 63;
    float2 w = tws[kk];
    float cc = w.x, ss = -w.y;
    int a0 = zp(f, kk), a1 = zp(f, kk + 64);
    float2 u = zs[a0], v = zs[a1];
    zs[a0] = f2add(u, v);
    zs[a1] = cmulf(cc, ss, f2sub(u, v));
  }
  __syncthreads();
  int fft = tid >> 5, i = tid & 31;
  #pragma unroll
  for (int s = 4; s >= 0; s -= 2) {
    int half = 1 << s;
    int kk1 = i & (half - 1);
    int base = ((i & ~(half - 1)) << 2) | kk1;
    int p0 = zp(fft, base),            p1 = zp(fft, base + half);
    int p2 = zp(fft, base + 2 * half), p3 = zp(fft, base + 3 * half);
    float2 q0 = zs[p0], q1 = zs[p1], q2 = zs[p2], q3 = zs[p3];
    float2 t1 = tws[kk1 << (6 - s)], t2 = tws[kk1 << (5 - s)];
    float c1 = t1.x, s1 = -t1.y;
    float c2 = t2.x, s2 = -t2.y;
    float c2b = -s2, s2b = c2;                  // +i * (c2, s2)
    float2 B0 = f2add(q0, q2);
    float2 B2 = cmulf(c2, s2, f2sub(q0, q2));
    float2 B1 = f2add(q1, q3);
    float2 B3 = cmulf(c2b, s2b, f2sub(q1, q3));
    zs[p0] = f2add(B0, B1);
    zs[p1] = cmulf(c1, s1, f2sub(B0, B1));
    zs[p2] = f2add(B2, B3);
    zs[p3] = cmulf(c1, s1, f2sub(B2, B3));
    __syncthreads();
  }
}

static __device__ __forceinline__ float h_filter(int f, const float* nf_s) {
  float coords = ((float)f + 0.5f) * (1.0f / 256.0f) - 0.5f;
  coords = clampf(coords, 0.0f, 63.0f);
  int i0 = (int)coords;
  int i1 = (i0 < 63) ? (i0 + 1) : 63;
  float w = coords - (float)i0;
  return nf_s[i0] * (1.0f - w) + nf_s[i1] * w;
}

static __device__ __forceinline__ float amp_lerp(int s, const float* amp_s) {
  float coords = ((float)s + 0.5f) * (1.0f / 256.0f) - 0.5f;
  coords = clampf(coords, 0.0f, 127.0f);
  int i0 = (int)coords;
  int i1 = (i0 < 127) ? (i0 + 1) : 127;
  float w = coords - (float)i0;
  float v = amp_s[i0] * (1.0f - w) + amp_s[i1] * w;
  return clampf(v, 0.0f, 1.0f);
}

// ---------------------------------------------------------------------------
// k1 body (run as kf1's blockIdx.y==0 slice, 128 threads): gumbel argmax ->
// f0 -> per-harmonic radians (f64); 128-frame env scan.
// env layout: env_ws[frame*1024 + channel]
// ---------------------------------------------------------------------------
static __device__ void k1_body(
    const float* __restrict__ packed, const float* __restrict__ gumbel,
    double* __restrict__ r64_ws, float* __restrict__ env_ws, int b, int tid) {
  __shared__ double zv[128];
  __shared__ int    zi[128];
  __shared__ double f0_sh;
  const float* pk = packed + b * 480;

  double u = (double)gumbel[b * 128 + tid];
  double t = -log(u + 1e-10);
  double g = -log(t + 1e-10);
  zv[tid] = (double)pk[tid] + g;
  zi[tid] = tid;
  __syncthreads();
  for (int s = 64; s > 0; s >>= 1) {
    if (tid < s) {
      double a = zv[tid], c = zv[tid + s];
      int ia = zi[tid], ic = zi[tid + s];
      if (c > a || (c == a && ic < ia)) { zv[tid] = c; zi[tid] = ic; }
    }
    __syncthreads();
  }
  if (tid == 0) {
    int note = zi[0];
    double Fd  = 440.0 * exp2(((double)(note - 69)) / 12.0) / 11025.0;
    float  F32 = (float)Fd;                     // FREQS is f32 in the reference
    double f0  = (double)F32 * 11025.0;
    f0 = (40.0 / 11025.0) + f0 * (3000.0 / 11025.0 - 40.0 / 11025.0);
    f0_sh = f0;
  }
  __syncthreads();
  if (tid < NHARM) {
    int h = tid;
    int c = b * NHARM + h;
    const float PIF = 3.14159265358979323846f;  // float32(np.pi)
    double osc = f0_sh * (double)(h + 1);
    r64_ws[c] = (osc / 11025.0) * (double)PIF;
    float ha = pk[384 + h];
    float hd = 0.1f + pk[400 + h] * 0.9f;
    float cur = 0.0f;
    for (int tt = 0; tt < NFRAMES; ++tt) {
      float a = pk[256 + tt] * 2.0f - 1.0f;
      cur = clampf(cur + a * ha, 0.0f, 1.0f);
      env_ws[tt * 1024 + c] = cur;
      cur = cur * hd;
    }
  }
}

// ---------------------------------------------------------------------------
// kernel 1 -- kf1: column FFTs (length 128 over n1) + W_M^{n2 k1} twiddle;
// blockIdx.y==0 runs k1. grid (BATCH, 33) x 128; 4 columns per FFT WG.
// ---------------------------------------------------------------------------
__global__ __launch_bounds__(128, 4) void kf1(
    const float* __restrict__ noise_u, float2* __restrict__ A,
    const float* __restrict__ packed, const float* __restrict__ gumbel,
    double* __restrict__ r64_ws, float* __restrict__ env_ws) {
  int b = blockIdx.x, tid = threadIdx.x;
  if (blockIdx.y == 0) { k1_body(packed, gumbel, r64_ws, env_ws, b, tid); return; }
  int tile = blockIdx.y - 1;
  __shared__ float2 zs[4 * ZROW];
  __shared__ float2 tws[64];
  tw_init(tws, tid);
  const float2* nu2 = (const float2*)(noise_u + (size_t)b * NSAMP);
  #pragma unroll
  for (int it = 0; it < 4; ++it) {
    int e = it * 128 + tid;
    int n1 = e >> 2, n2l = e & 3;
    float2 xv = nu2[n1 * 128 + tile * 4 + n2l];
    zs[zp(n2l, brev7(n1))] = make_float2(xv.x * 2.0f - 1.0f, xv.y * 2.0f - 1.0f);
  }
  __syncthreads();
  fft128_r4<128, false>(zs, tws, tid);
  float2* Ab = A + (size_t)b * MFFT;
  #pragma unroll
  for (int it = 0; it < 4; ++it) {
    int e = it * 128 + tid;
    int k1 = e >> 2, n2l = e & 3;
    int n2 = tile * 4 + n2l;
    float2 v = zs[zp(n2l, k1)];
    float ang = -(2.0f * (float)M_PI / 16384.0f) * (float)(k1 * n2);
    float ss, cc; __sincosf(ang, &ss, &cc);
    Ab[k1 * 128 + n2] = make_float2(cc * v.x - ss * v.y, cc * v.y + ss * v.x);
  }
}

// ---------------------------------------------------------------------------
// kernel 2 -- kmid: fused row-FFT (fwd) -> Hermitian filter (LDS) ->
// row-IFFT (DIF) -> conj twiddle. 4 rows = 2 pair-groups per WG:
// r in {0,1}: k1 = t*2+r;  r in {2,3}: k1 = pair(t*2+r-2), pair(0)=64.
// grid (BATCH, 32) x 128
// ---------------------------------------------------------------------------
__global__ __launch_bounds__(128, 4) void kmid(
    const float* __restrict__ packed, float2* __restrict__ A) {
  __shared__ float2 zs[4 * ZROW];
  __shared__ float2 tws[64];
  __shared__ float  nf_s[64];
  __shared__ int    rowk1[4];
  int b = blockIdx.x, t = blockIdx.y, tid = threadIdx.x;
  tw_init(tws, tid);
  if (tid >= 64 && tid < 128) nf_s[tid - 64] = packed[b * 480 + 416 + (tid - 64)];
  if (tid < 4) {
    int s = tid & 1;
    int m = t * 2 + s;
    rowk1[tid] = (tid < 2) ? m : ((m == 0) ? 64 : 128 - m);
  }
  __syncthreads();
  float2* Ab = A + (size_t)b * MFFT;

  // load 4 rows, bitrev over k2
  #pragma unroll
  for (int it = 0; it < 4; ++it) {
    int e = it * 128 + tid;
    int r = e >> 7, n2 = e & 127;
    zs[zp(r, brev7(n2))] = Ab[rowk1[r] * 128 + n2];
  }
  __syncthreads();
  fft128_r4<128, false>(zs, tws, tid);   // zs[zp(r,k2)] = Z[rowk1[r] + 128*k2]

  // Hermitian unpack * H/M * repack; pair (k1,k2) <-> (128-k1, 127-k2),
  // each unordered pair owned by exactly one task (k2 <= 63).
  const float hsc = 1.0f / 16384.0f;
  #pragma unroll
  for (int it = 0; it < 2; ++it) {
    int task = it * 128 + tid;      // 256 tasks: (local row r, k2 in 0..63)
    int r  = task >> 6;
    int k2 = task & 63;
    int k1 = rowk1[r];
    int f = k1 + (k2 << 7);
    if (f == 0) {                   // DC and f=8192 specials (WG t=0 only)
      float2 Z0 = zs[zp(0, 0)];
      float X0 = Z0.x + Z0.y;
      float Y0 = X0 * (h_filter(0, nf_s) * hsc);
      zs[zp(0, 0)] = make_float2(0.5f * Y0, 0.5f * Y0);   // H[M]=0 -> YM=0
      float Hm = h_filter(8192, nf_s) * hsc;
      float2 Zm = zs[zp(0, 64)];
      zs[zp(0, 64)] = make_float2(Zm.x * Hm, Zm.y * Hm);
    } else {
      int g = 16384 - f;
      int k1g = g & 127;
      int pr = (k1g == k1) ? r : ((r < 2) ? r + 2 : r - 2);
      int k2p = g >> 7;
      float2 Zf = zs[zp(r, k2)], Zg = zs[zp(pr, k2p)];
      float Ax = 0.5f * (Zf.x + Zg.x), Ay = 0.5f * (Zf.y - Zg.y);
      float Bx = 0.5f * (Zf.x - Zg.x), By = 0.5f * (Zf.y + Zg.y);
      float ang = (-(float)M_PI / (float)MFFT) * (float)f;
      float ss, cc; __sincosf(ang, &ss, &cc);
      float WBx = cc * Bx - ss * By, WBy = cc * By + ss * Bx;
      float Hf = h_filter(f, nf_s) * hsc;
      float Hg = h_filter(g, nf_s) * hsc;
      float Yfx = (Ax + WBy) * Hf, Yfy = (Ay - WBx) * Hf;
      float Ygx = (Ax - WBy) * Hg, Ygy = (-Ay - WBx) * Hg;
      float A2x = 0.5f * (Yfx + Ygx), A2y = 0.5f * (Yfy - Ygy);
      float B2x = 0.5f * (Yfx - Ygx), B2y = 0.5f * (Yfy + Ygy);
      float CBx = cc * B2x + ss * B2y;
      float CBy = cc * B2y - ss * B2x;
      zs[zp(r, k2)]   = make_float2(A2x - CBy, A2y + CBx);
      float DBx = cc * B2x + ss * B2y;
      float DBy = ss * B2x - cc * B2y;
      zs[zp(pr, k2p)] = make_float2(A2x - DBy, -A2y + DBx);
    }
  }
  __syncthreads();

  fft128_r4_dif_inv<128>(zs, tws, tid);  // natural -> bitrev

  // store, un-bitrev + conj twiddle
  #pragma unroll
  for (int it = 0; it < 4; ++it) {
    int e = it * 128 + tid;
    int r = e >> 7, n2 = e & 127;
    int k1 = rowk1[r];
    float2 v = zs[zp(r, brev7(n2))];
    float ang = (2.0f * (float)M_PI / 16384.0f) * (float)(k1 * n2);
    float ss, cc; __sincosf(ang, &ss, &cc);
    Ab[k1 * 128 + n2] = make_float2(cc * v.x - ss * v.y, cc * v.y + ss * v.x);
  }
}

// ---------------------------------------------------------------------------
// kernel 3 -- ki2: column inverse FFTs (over k1) + amp*clip -> ws2
// (per-batch samples). grid (BATCH, 32) x 128; 4 columns per WG.
// ---------------------------------------------------------------------------
__global__ __launch_bounds__(128, 4) void ki2(
    const float* __restrict__ packed, const float2* __restrict__ A,
    float2* __restrict__ ws2) {
  __shared__ float2 zs[4 * ZROW];
  __shared__ float2 tws[64];
  __shared__ float amp_s[128];
  int b = blockIdx.x, tile = blockIdx.y, tid = threadIdx.x;
  tw_init(tws, tid);
  amp_s[tid] = packed[b * 480 + 256 + tid] * 2.0f - 1.0f;
  const float2* Ab = A + (size_t)b * MFFT;
  #pragma unroll
  for (int it = 0; it < 4; ++it) {
    int e = it * 128 + tid;
    int k1 = e >> 2, n2l = e & 3;
    zs[zp(n2l, brev7(k1))] = Ab[k1 * 128 + tile * 4 + n2l];
  }
  __syncthreads();
  fft128_r4<128, true>(zs, tws, tid);
  float2* W2 = ws2 + (size_t)b * MFFT;
  #pragma unroll
  for (int it = 0; it < 4; ++it) {
    int e = it * 128 + tid;
    int n1 = e >> 2, n2l = e & 3;
    int n2 = tile * 4 + n2l;
    int n = n1 * 128 + n2;
    float2 v = zs[zp(n2l, n1)];
    v.x *= amp_lerp(2 * n,     amp_s);
    v.y *= amp_lerp(2 * n + 1, amp_s);
    W2[n] = v;
  }
}

// ---------------------------------------------------------------------------
// kernel 4 -- k3r: oscillator bank (Chebyshev harmonic recurrence) +
// batch-mean of noise, fused. 256 WGs x 1024 thr; WG k covers 128 samples;
// wave lane = batch channel. Plain stores (covers out once; un-poisons it).
// ---------------------------------------------------------------------------
__global__ __launch_bounds__(1024) void k3r(
    const double* __restrict__ r64_ws, const float* __restrict__ env_ws,
    const float* __restrict__ ws2f, float* __restrict__ out) {
  __shared__ float oscs[128];
  __shared__ float nse[8][128];
  const double TWO_PI     = 6.283185307179586476925286766559;
  const double INV_TWO_PI = 0.15915494309189533576888376337251;
  int tid = threadIdx.x;
  int lane = tid & 63;               // batch
  int wv = tid >> 6;                 // sample group (0..15), 8 samples each
  int k = blockIdx.x;                // 128-sample chunk
  int s0 = k * 128;
  int K = k >> 1, half = k & 1;

  double r0 = r64_ws[lane * 16];     // fundamental step angle (f64)
  double rr = r0 - rint(r0 * INV_TWO_PI) * TWO_PI;
  double x0 = (double)(s0 + wv * 8 + 1) * r0;
  double ph = x0 - rint(x0 * INV_TWO_PI) * TWO_PI;
  float s1, c1, srot, crot;
  __sincosf((float)ph, &s1, &c1);
  __sincosf((float)rr, &srot, &crot);

  int km1 = (K > 0) ? (K - 1) : 0;
  int kp1 = (K < 127) ? (K + 1) : 127;
  int fA = half ? K : km1;
  int fB = half ? kp1 : K;
  const float4* eA = (const float4*)(env_ws + fA * 1024 + lane * 16);
  const float4* eB = (const float4*)(env_ws + fB * 1024 + lane * 16);
  float ev[16], sl[16];
  float basew = (half ? 0.5f : 128.5f) + (float)(wv * 8);
  #pragma unroll
  for (int q = 0; q < 4; ++q) {
    float4 a = eA[q], bb = eB[q];
    float d;
    d = (bb.x - a.x) * (1.0f / 256.0f); sl[q*4+0] = d; ev[q*4+0] = a.x + d * basew;
    d = (bb.y - a.y) * (1.0f / 256.0f); sl[q*4+1] = d; ev[q*4+1] = a.y + d * basew;
    d = (bb.z - a.z) * (1.0f / 256.0f); sl[q*4+2] = d; ev[q*4+2] = a.z + d * basew;
    d = (bb.w - a.w) * (1.0f / 256.0f); sl[q*4+3] = d; ev[q*4+3] = a.w + d * basew;
  }

  #pragma unroll
  for (int j = 0; j < 8; ++j) {
    float twoC = c1 + c1;
    float sm1 = 0.0f, sc = s1;
    float acc = ev[0] * sc; ev[0] += sl[0];
    #pragma unroll
    for (int i = 1; i < 16; ++i) {
      float sn = fmaf(twoC, sc, -sm1);
      sm1 = sc; sc = sn;
      acc = fmaf(ev[i], sn, acc);
      ev[i] += sl[i];
    }
    acc += __shfl_xor(acc, 32);
    acc += __shfl_xor(acc, 16);
    acc += __shfl_xor(acc, 8);
    acc += __shfl_xor(acc, 4);
    acc += __shfl_xor(acc, 2);
    acc += __shfl_xor(acc, 1);
    if (lane == 0) oscs[wv * 8 + j] = acc;
    float tn = fmaf(s1, crot, c1 * srot);      // uses old s1,c1
    c1 = fmaf(c1, crot, -(s1 * srot));
    s1 = tn;
  }
  __syncthreads();

  // batch-mean of noise: 8 groups x 8 batches each, coalesced rows
  {
    int j = tid & 127, grp = tid >> 7;
    const float* src = ws2f + (size_t)(grp * 8) * NSAMP + s0 + j;
    float acc = 0.0f;
    #pragma unroll
    for (int bb = 0; bb < 8; ++bb) acc += src[(size_t)bb * NSAMP];
    nse[grp][j] = acc;
  }
  __syncthreads();

  if (tid < 128) {
    float nz = 0.0f;
    #pragma unroll
    for (int g = 0; g < 8; ++g) nz += nse[g][tid];
    out[s0 + tid] = oscs[tid] * (1.0f / 1024.0f) + nz * (1.0f / 64.0f);
  }
}

// ---------------------------------------------------------------------------
extern "C" void kernel_launch(void* const* d_in, const int* in_sizes, int n_in,
                              void* d_out, int out_size, void* d_ws, size_t ws_size,
                              hipStream_t stream) {
  const float* packed  = (const float*)d_in[0];
  const float* gumbel  = (const float*)d_in[1];
  const float* noise_u = (const float*)d_in[2];
  float* out = (float*)d_out;

  // ws layout: [r64 8KB][env 512KB][A 8MB][ws2 8MB]
  char* wsc = (char*)d_ws;
  double* r64_ws = (double*)wsc;
  float*  env_ws = (float*)(wsc + 8192);
  float2* A      = (float2*)(wsc + 8192 + 524288);
  float2* ws2    = (float2*)(wsc + 8192 + 524288 + (size_t)BATCH * MFFT * 8);

  kf1 <<<dim3(BATCH, 33), 128, 0, stream>>>(noise_u, A, packed, gumbel, r64_ws, env_ws);
  kmid<<<dim3(BATCH, 32), 128, 0, stream>>>(packed, A);
  ki2 <<<dim3(BATCH, 32), 128, 0, stream>>>(packed, A, ws2);
  k3r <<<256, 1024, 0, stream>>>(r64_ws, env_ws, (const float*)ws2, out);
}